// Round 6
// baseline (570.905 us; speedup 1.0000x reference)
//
#include <hip/hip_runtime.h>
#include <hip/hip_bf16.h>
#include <math.h>

#define NF 32
#define NH 160
#define NB 64
#define NT 256
#define NBT (NB*NT)
#define TB 32      // (b,t) rows per block in k3
#define LN_EPS 1e-3f

typedef __attribute__((ext_vector_type(8))) short short8;
typedef __attribute__((ext_vector_type(4))) float f32x4;

__device__ __forceinline__ unsigned short f2bf(float f) {
  __hip_bfloat16 b = __float2bfloat16(f);
  return *reinterpret_cast<unsigned short*>(&b);
}
__device__ __forceinline__ float fexp(float z) { return __expf(z); }
__device__ __forceinline__ float felu(float z) {
  return z > 0.f ? z : __expf(z) - 1.f;
}
__device__ __forceinline__ float fsigmoid(float z) {
  return __builtin_amdgcn_rcpf(1.f + __expf(-z));
}

// sum across each 32-lane half of the wave
__device__ __forceinline__ float half_sum(float v) {
  v += __shfl_xor(v, 1);
  v += __shfl_xor(v, 2);
  v += __shfl_xor(v, 4);
  v += __shfl_xor(v, 8);
  v += __shfl_xor(v, 16);
  return v;
}
// sum across 16-lane groups (l15)
__device__ __forceinline__ float sum16(float v) {
  v += __shfl_xor(v, 1);
  v += __shfl_xor(v, 2);
  v += __shfl_xor(v, 4);
  v += __shfl_xor(v, 8);
  return v;
}

// ---- kernel 0: W2 (f,h,k) fp32 -> MFMA B-fragment order bf16 in ws ----
// frag[((f*10+ct)*5+hs)*64 + l] (short8): elem j = W2[f][hs*32+(l>>4)*8+j][ct*16+(l&15)]
// (replicates the HW-verified round-5 B-read pattern exactly)
__global__ __launch_bounds__(256) void k0_w2frag(
    const float* __restrict__ W2, short8* __restrict__ w2f)
{
  const int f = blockIdx.x, tid = threadIdx.x;
  const float* W2f = W2 + (size_t)f * NH * NH;
  for (int i = tid; i < 3200; i += 256) {
    const int l = i & 63, fr = i >> 6;     // fr = ct*5+hs
    const int hs = fr % 5, ct = fr / 5;
    const int lg = l >> 4, l15 = l & 15;
    const int h0 = hs * 32 + lg * 8;
    const int k = ct * 16 + l15;
    short8 v;
#pragma unroll
    for (int j = 0; j < 8; ++j) v[j] = (short)f2bf(W2f[(size_t)(h0 + j) * NH + k]);
    w2f[(((size_t)f * 10 + ct) * 5 + hs) * 64 + l] = v;
  }
}

// ---------------- kernel 1: softmax weights (B,F) ----------------
__global__ __launch_bounds__(256) void k1_weights(
    const float* __restrict__ x, const float* __restrict__ Ww,
    const float* __restrict__ bw, float* __restrict__ wout)
{
  __shared__ float red[256][NF + 1];
  __shared__ float red2[NF][8];
  const int b = blockIdx.x, tid = threadIdx.x;
  float acc[NF];
#pragma unroll
  for (int j = 0; j < NF; ++j) acc[j] = 0.f;
  const float* xb = x + (size_t)b * (NT * NF);
  for (int i = tid; i < NT * NF; i += 256) {
    const float xv = xb[i];
    const float4* wr = (const float4*)(Ww + (size_t)i * NF);
#pragma unroll
    for (int j4 = 0; j4 < NF / 4; ++j4) {
      const float4 wv = wr[j4];
      acc[4*j4+0] = fmaf(xv, wv.x, acc[4*j4+0]);
      acc[4*j4+1] = fmaf(xv, wv.y, acc[4*j4+1]);
      acc[4*j4+2] = fmaf(xv, wv.z, acc[4*j4+2]);
      acc[4*j4+3] = fmaf(xv, wv.w, acc[4*j4+3]);
    }
  }
#pragma unroll
  for (int j = 0; j < NF; ++j) red[tid][j] = acc[j];
  __syncthreads();
  {
    const int j = tid >> 3, part = tid & 7;
    float s = 0.f;
    for (int t = part; t < 256; t += 8) s += red[t][j];
    red2[j][part] = s;
  }
  __syncthreads();
  if (tid < NF) {
    float s = 0.f;
#pragma unroll
    for (int p = 0; p < 8; ++p) s += red2[tid][p];
    s += bw[tid];
    float m = s;
    m = fmaxf(m, __shfl_xor(m, 1));
    m = fmaxf(m, __shfl_xor(m, 2));
    m = fmaxf(m, __shfl_xor(m, 4));
    m = fmaxf(m, __shfl_xor(m, 8));
    m = fmaxf(m, __shfl_xor(m, 16));
    const float e = expf(s - m);
    float ssum = e;
    ssum += __shfl_xor(ssum, 1);
    ssum += __shfl_xor(ssum, 2);
    ssum += __shfl_xor(ssum, 4);
    ssum += __shfl_xor(ssum, 8);
    ssum += __shfl_xor(ssum, 16);
    wout[b * NF + tid] = e / ssum;
  }
}

// ------- kernel 2: barrier-free MFMA GRN + LN + weighted combine -------
// 256 thr = 4 waves; wave w owns rows bt0 + w*16 .. +15, ALL 160 cols.
// Per f: A-frags computed in-register (a1 = elu(x*W1+b1) bf16),
// B-frags read frag-ordered from L2-resident ws, 50 MFMA,
// epilogue fully in-register with 16-lane shuffle LN.
__global__ __launch_bounds__(256) void k2_mfma(
    const float* __restrict__ x, const float* __restrict__ W1,
    const float* __restrict__ b1, const short8* __restrict__ w2f,
    const float* __restrict__ b2, const float* __restrict__ Wg,
    const float* __restrict__ bg, const float* __restrict__ lng,
    const float* __restrict__ lnb, const float* __restrict__ wts,
    float* __restrict__ comb)
{
  __shared__ float xs_t[NF * 64];   // [f][row] transposed
  const int tid = threadIdx.x;
  const int l = tid & 63, w = tid >> 6;
  const int l15 = l & 15, lg = l >> 4;
  const int bt0 = blockIdx.x * 64;
  const int b = bt0 >> 8;

  // load x transposed (strided gmem read, conflict-free LDS write; one-time)
  for (int i = tid; i < 64 * NF; i += 256) {
    const int r = i & 63, f = i >> 6;
    xs_t[f * 64 + r] = x[(size_t)(bt0 + r) * NF + f];
  }
  __syncthreads();

  float cacc[4][10];
#pragma unroll
  for (int q = 0; q < 4; ++q)
#pragma unroll
    for (int ct = 0; ct < 10; ++ct) cacc[q][ct] = 0.f;

  for (int f = 0; f < NF; ++f) {
    const float* W1f = W1 + f * NH;
    const float* b1f = b1 + f * NH;
    // ---- A-frags in-register: row = w*16 + l15, h = hs*32 + lg*8 + j ----
    const float xva = xs_t[f * 64 + w * 16 + l15];
    short8 af[5];
#pragma unroll
    for (int hs = 0; hs < 5; ++hs) {
      const int h0 = hs * 32 + lg * 8;
      const float4 wA = *(const float4*)(W1f + h0);
      const float4 wB = *(const float4*)(W1f + h0 + 4);
      const float4 bA = *(const float4*)(b1f + h0);
      const float4 bB = *(const float4*)(b1f + h0 + 4);
      short8 v;
      v[0] = (short)f2bf(felu(fmaf(xva, wA.x, bA.x)));
      v[1] = (short)f2bf(felu(fmaf(xva, wA.y, bA.y)));
      v[2] = (short)f2bf(felu(fmaf(xva, wA.z, bA.z)));
      v[3] = (short)f2bf(felu(fmaf(xva, wA.w, bA.w)));
      v[4] = (short)f2bf(felu(fmaf(xva, wB.x, bB.x)));
      v[5] = (short)f2bf(felu(fmaf(xva, wB.y, bB.y)));
      v[6] = (short)f2bf(felu(fmaf(xva, wB.z, bB.z)));
      v[7] = (short)f2bf(felu(fmaf(xva, wB.w, bB.w)));
      af[hs] = v;
    }
    // ---- MFMA: 10 col-tiles x 5 K-steps, B direct from L2 ----
    f32x4 acc[10];
#pragma unroll
    for (int ct = 0; ct < 10; ++ct) acc[ct] = f32x4{0.f, 0.f, 0.f, 0.f};
    const short8* bf_f = w2f + (size_t)f * 50 * 64;
#pragma unroll
    for (int ct = 0; ct < 10; ++ct) {
#pragma unroll
      for (int hs = 0; hs < 5; ++hs) {
        const short8 bfr = bf_f[(ct * 5 + hs) * 64 + l];
        acc[ct] = __builtin_amdgcn_mfma_f32_16x16x32_bf16(af[hs], bfr, acc[ct], 0, 0, 0);
      }
    }
    // ---- epilogue: gate + within-wave LN + weighted accumulate ----
    // lane holds rows (lg*4+q), cols k = ct*16+l15
    const float wf = wts[b * NF + f];
    float xvq[4];
#pragma unroll
    for (int q = 0; q < 4; ++q) xvq[q] = xs_t[f * 64 + w * 16 + lg * 4 + q];
    float feat[4][10];
    float s1[4] = {0.f, 0.f, 0.f, 0.f};
#pragma unroll
    for (int ct = 0; ct < 10; ++ct) {
      const int k = ct * 16 + l15;
      const float b2v = b2[f * NH + k];
      const float wgv = Wg[f * NH + k];
      const float bgv = bg[f * NH + k];
#pragma unroll
      for (int q = 0; q < 4; ++q) {
        const float aa = acc[ct][q] + b2v;
        const float g = fsigmoid(fmaf(xvq[q], wgv, bgv));
        const float ft = fmaf(g, aa - xvq[q], xvq[q]);
        feat[q][ct] = ft;
        s1[q] += ft;
      }
    }
#pragma unroll
    for (int q = 0; q < 4; ++q) {
      const float mean = sum16(s1[q]) * (1.f / NH);
      float var = 0.f;
#pragma unroll
      for (int ct = 0; ct < 10; ++ct) {
        const float d = feat[q][ct] - mean;
        var = fmaf(d, d, var);
      }
      var = sum16(var);
      const float inv = __builtin_amdgcn_rsqf(var * (1.f / NH) + LN_EPS);
      const float winv = wf * inv;
#pragma unroll
      for (int ct = 0; ct < 10; ++ct) {
        const int k = ct * 16 + l15;
        const float ln = (feat[q][ct] - mean) * winv * lng[f * NH + k] + ((wf) * lnb[f * NH + k]);
        cacc[q][ct] += ln;
      }
    }
  }
#pragma unroll
  for (int q = 0; q < 4; ++q) {
    const size_t row = bt0 + w * 16 + lg * 4 + q;
#pragma unroll
    for (int ct = 0; ct < 10; ++ct)
      comb[row * NH + ct * 16 + l15] = cacc[q][ct];
  }
}

// ---------------- kernel 3: output GRN + LN (in-place on d_out) ----------------
__global__ __launch_bounds__(256) void k3_outgrn(
    float* io,
    const float* __restrict__ oW1, const float* __restrict__ ob1,
    const float* __restrict__ oW2, const float* __restrict__ ob2,
    const float* __restrict__ oWg, const float* __restrict__ obg,
    const float* __restrict__ olng, const float* __restrict__ olnb)
{
  __shared__ float cs[TB * NH];
  __shared__ float oas[TB * NH];
  const int tid = threadIdx.x;
  const int bt0 = blockIdx.x * TB;
  const int kl = tid & 31, rt = tid >> 5;
  for (int i = tid; i < TB * NH; i += 256) cs[i] = io[(size_t)bt0 * NH + i];
  __syncthreads();

  float oga[4][5], a1a[4][5];
#pragma unroll
  for (int q = 0; q < 4; ++q)
#pragma unroll
    for (int j = 0; j < 5; ++j) { oga[q][j] = 0.f; a1a[q][j] = 0.f; }

  for (int h = 0; h < NH; ++h) {
    float cv[4];
#pragma unroll
    for (int q = 0; q < 4; ++q) cv[q] = cs[(rt + 8 * q) * NH + h];
#pragma unroll
    for (int j = 0; j < 5; ++j) {
      const float wg = oWg[h * NH + kl + 32 * j];
      const float w1 = oW1[h * NH + kl + 32 * j];
#pragma unroll
      for (int q = 0; q < 4; ++q) {
        oga[q][j] = fmaf(cv[q], wg, oga[q][j]);
        a1a[q][j] = fmaf(cv[q], w1, a1a[q][j]);
      }
    }
  }
#pragma unroll
  for (int q = 0; q < 4; ++q)
#pragma unroll
    for (int j = 0; j < 5; ++j) {
      const int k = kl + 32 * j;
      oas[(rt + 8 * q) * NH + k] = felu(a1a[q][j] + ob1[k]);
    }
  __syncthreads();

  float o2a[4][5];
#pragma unroll
  for (int q = 0; q < 4; ++q)
#pragma unroll
    for (int j = 0; j < 5; ++j) o2a[q][j] = 0.f;
  for (int h = 0; h < NH; ++h) {
    float av[4];
#pragma unroll
    for (int q = 0; q < 4; ++q) av[q] = oas[(rt + 8 * q) * NH + h];
#pragma unroll
    for (int j = 0; j < 5; ++j) {
      const float w2v = oW2[h * NH + kl + 32 * j];
#pragma unroll
      for (int q = 0; q < 4; ++q) o2a[q][j] = fmaf(av[q], w2v, o2a[q][j]);
    }
  }
#pragma unroll
  for (int q = 0; q < 4; ++q) {
    const int row = rt + 8 * q;
    float feat[5];
    float s1 = 0.f;
#pragma unroll
    for (int j = 0; j < 5; ++j) {
      const int k = kl + 32 * j;
      const float oa2 = o2a[q][j] + ob2[k];
      const float g = fsigmoid(oga[q][j] + obg[k]);
      const float c = cs[row * NH + k];
      const float ft = fmaf(g, oa2 - c, c);
      feat[j] = ft;
      s1 += ft;
    }
    s1 = half_sum(s1);
    const float mean = s1 * (1.f / NH);
    float s2 = 0.f;
#pragma unroll
    for (int j = 0; j < 5; ++j) {
      const float d = feat[j] - mean;
      s2 = fmaf(d, d, s2);
    }
    s2 = half_sum(s2);
    const float inv = __builtin_amdgcn_rsqf(s2 * (1.f / NH) + LN_EPS);
#pragma unroll
    for (int j = 0; j < 5; ++j) {
      const int k = kl + 32 * j;
      io[(size_t)(bt0 + row) * NH + k] =
          (feat[j] - mean) * inv * olng[k] + olnb[k];
    }
  }
}

extern "C" void kernel_launch(void* const* d_in, const int* in_sizes, int n_in,
                              void* d_out, int out_size, void* d_ws, size_t ws_size,
                              hipStream_t stream) {
  const float* x   = (const float*)d_in[0];
  const float* W1  = (const float*)d_in[1];
  const float* b1  = (const float*)d_in[2];
  const float* W2  = (const float*)d_in[3];
  const float* b2  = (const float*)d_in[4];
  const float* Wg  = (const float*)d_in[5];
  const float* bg  = (const float*)d_in[6];
  const float* lng = (const float*)d_in[7];
  const float* lnb = (const float*)d_in[8];
  const float* Ww  = (const float*)d_in[9];
  const float* bw  = (const float*)d_in[10];
  const float* oW1 = (const float*)d_in[11];
  const float* ob1 = (const float*)d_in[12];
  const float* oW2 = (const float*)d_in[13];
  const float* ob2 = (const float*)d_in[14];
  const float* oWg = (const float*)d_in[15];
  const float* obg = (const float*)d_in[16];
  const float* olng= (const float*)d_in[17];
  const float* olnb= (const float*)d_in[18];

  float* out  = (float*)d_out;
  float* wout = out + (size_t)NBT * NH;       // weights4 region of d_out
  short8* w2f = (short8*)d_ws;                // 32*10*5*64*16B = 1.64 MB

  k0_w2frag<<<NF, 256, 0, stream>>>(W2, w2f);
  k1_weights<<<NB, 256, 0, stream>>>(x, Ww, bw, wout);
  k2_mfma<<<NBT / 64, 256, 0, stream>>>(x, W1, b1, w2f, b2, Wg, bg, lng, lnb,
                                        wout, out);
  k3_outgrn<<<NBT / TB, 256, 0, stream>>>(out, oW1, ob1, oW2, ob2, oWg, obg,
                                          olng, olnb);
}